// Round 7
// baseline (317.236 us; speedup 1.0000x reference)
//
#include <hip/hip_runtime.h>
#include <math.h>

#define H 512
#define W 512
#define RM 8
#define TSX 32
#define TSY 16
#define PPT 2
#define LW (TSX + 2*RM)       // 48
#define LH (TSY + 2*RM)       // 32
#define PL (LH * LW)          // 1536 float4 = 24.6 KB -> 6 blocks/CU
#define BIGNEG -200.0f        // masked bias: ldexp(p,-200) underflows to exact 0

// software exp2: 6 full-rate VALU ops (v_exp_f32 measured ~32 cy/wave across
// R0/R2/R3 fits; this is ~12 cy). quadratic minimax, rel err ~0.17%.
__device__ __forceinline__ float exp2q(float x) {
    float n = __builtin_rintf(x);                      // v_rndne_f32
    float f = x - n;                                   // [-0.5, 0.5]
    float p = fmaf(f, fmaf(f, 0.33718944f, 0.65763628f), 1.0017247f);
    return ldexpf(p, (int)n);                          // v_cvt_i32 + v_ldexp
}

__global__ __launch_bounds__(256, 4) void bilateral_kernel(
    const float* __restrict__ img, const float* __restrict__ params,
    float* __restrict__ out)
{
    __shared__ float4 tile[PL];

    const int n  = blockIdx.z;
    const int x0 = blockIdx.x * TSX;
    const int y0 = blockIdx.y * TSY;

    const float p0 = params[n*3 + 0];
    const float p1 = params[n*3 + 1];
    const float p2 = params[n*3 + 2];
    const int win = ((int)p0) * 14 + 3;       // window = int(p0)*7*2 + 3
    const int r   = (win - 1) >> 1;
    const float sc = fmaf(p1, 99.0f, 1.0f);
    const float ss = fmaf(p2, 99.0f, 1.0f);
    const float LOG2E = 1.4426950408889634f;
    const float A  = -65025.0f * LOG2E / (2.0f * sc * sc);  // A < 0
    const float Bs = -LOG2E / (2.0f * ss * ss);

    // ---- stage tile + halo; w = q = A*(s.s) ----
    const float* imgN = img + (size_t)n * (3 * H * W);
    for (int idx = threadIdx.x; idx < PL; idx += 256) {
        int ly = idx / LW;
        int lx = idx - ly * LW;
        int gy = y0 + ly - RM; gy = gy < 0 ? 0 : (gy > H-1 ? H-1 : gy);
        int gx = x0 + lx - RM; gx = gx < 0 ? 0 : (gx > W-1 ? W-1 : gx);
        int g = gy * W + gx;
        float vr = imgN[g];
        float vg = imgN[H*W + g];
        float vb = imgN[2*H*W + g];
        tile[idx] = make_float4(vr, vg, vb,
                                A * fmaf(vr, vr, fmaf(vg, vg, vb * vb)));
    }
    __syncthreads();

    const int tx   = threadIdx.x & (TSX - 1);
    const int tq   = threadIdx.x >> 5;        // 0..7
    const int base = tq * PPT;

    // per-center constants — named scalars only (no pointer-passed arrays)
    const float m2A = -2.0f * A;
    float4 c0 = tile[(RM + base + 0) * LW + (RM + tx)];
    float4 c1 = tile[(RM + base + 1) * LW + (RM + tx)];
    const float K0  = c0.w,        K1  = c1.w;
    const float r20 = m2A * c0.x,  r21 = m2A * c1.x;
    const float g20 = m2A * c0.y,  g21 = m2A * c1.y;
    const float b20 = m2A * c0.z,  b21 = m2A * c1.z;

    float a0r = 0.0f, a0g = 0.0f, a0b = 0.0f, a0d = 0.0f;
    float a1r = 0.0f, a1g = 0.0f, a1b = 0.0f, a1d = 0.0f;

    // spatial-x bias — uniform (SALU/SGPR); only constant-indexed (unrolled)
    float bx[2*RM + 1];
    #pragma unroll
    for (int i = 0; i <= 2*RM; ++i) {
        int d  = i - RM;
        int ad = d < 0 ? -d : d;
        bx[i] = (ad <= r) ? Bs * (float)(d*d) : BIGNEG;
    }

    #pragma unroll 1
    for (int j = 0; j < 2*RM + PPT; ++j) {    // 18 rows
        int dy0  = j - RM;                    // center 0
        int dy1  = j - RM - 1;                // center 1
        int ad0 = dy0 < 0 ? -dy0 : dy0;
        int ad1 = dy1 < 0 ? -dy1 : dy1;
        const float ck0 = K0 + ((ad0 <= r) ? Bs * (float)(dy0*dy0) : BIGNEG);
        const float ck1 = K1 + ((ad1 <= r) ? Bs * (float)(dy1*dy1) : BIGNEG);

        const int rb = (base + j) * LW + tx;
        #pragma unroll
        for (int i = 0; i <= 2*RM; ++i) {
            float4 s = tile[rb + i];          // ds_read_b128
            float qb = s.w + bx[i];           // shared across both centers

            float t0 = fmaf(b20, s.z, qb + ck0);
            t0 = fmaf(g20, s.y, t0);
            t0 = fmaf(r20, s.x, t0);
            float w0 = exp2q(t0);
            a0r = fmaf(w0, s.x, a0r);
            a0g = fmaf(w0, s.y, a0g);
            a0b = fmaf(w0, s.z, a0b);
            a0d += w0;

            float t1 = fmaf(b21, s.z, qb + ck1);
            t1 = fmaf(g21, s.y, t1);
            t1 = fmaf(r21, s.x, t1);
            float w1 = exp2q(t1);
            a1r = fmaf(w1, s.x, a1r);
            a1g = fmaf(w1, s.y, a1g);
            a1b = fmaf(w1, s.z, a1b);
            a1d += w1;
        }
    }

    float* outN = out + (size_t)n * (3 * H * W);
    const float inv0 = __builtin_amdgcn_rcpf(a0d);
    const float inv1 = __builtin_amdgcn_rcpf(a1d);
    const int o0 = (y0 + base + 0) * W + (x0 + tx);
    const int o1 = (y0 + base + 1) * W + (x0 + tx);
    outN[o0]         = a0r * inv0;
    outN[H*W + o0]   = a0g * inv0;
    outN[2*H*W + o0] = a0b * inv0;
    outN[o1]         = a1r * inv1;
    outN[H*W + o1]   = a1g * inv1;
    outN[2*H*W + o1] = a1b * inv1;
}

extern "C" void kernel_launch(void* const* d_in, const int* in_sizes, int n_in,
                              void* d_out, int out_size, void* d_ws, size_t ws_size,
                              hipStream_t stream) {
    const float* img    = (const float*)d_in[0];
    const float* params = (const float*)d_in[1];
    float* out          = (float*)d_out;
    dim3 grid(W / TSX, H / TSY, 8);
    bilateral_kernel<<<grid, dim3(256), 0, stream>>>(img, params, out);
}

// Round 8
// 300.221 us; speedup vs baseline: 1.0567x; 1.0567x over previous
//
#include <hip/hip_runtime.h>
#include <math.h>

#define H 512
#define W 512
#define RM 8
#define TSX 32
#define TSY 16
#define PPT 2
#define LW (TSX + 2*RM)       // 48
#define LH (TSY + 2*RM)       // 32
#define PL (LH * LW)          // 1536 float4 = 24.6 KB -> 6 blocks/CU
#define BIGNEG -10000.0f      // masked bias; clamped to -126 -> w ~ 1e-38 ~ 0
#define MAGIC 12582912.0f     // 1.5 * 2^23

// exp2 with ONLY guaranteed-full-rate ops (fp add/sub/mul/fma + int shl/add).
// R6 lesson: v_rndne/v_cvt_i32/v_ldexp are ~16 cy/wave (trans-class), v_exp_f32
// ~32 cy; this sequence is 8 ops * 2 cy. Requires x in [-126, ~30].
// n captured by magic-add; scale 2^n = bitcast((bits(y)<<23) + 0x3F800000).
__device__ __forceinline__ float exp2_fast(float x) {
    float y = x + MAGIC;                    // RNE int capture (fp add)
    float z = y - MAGIC;                    // n as float (exact)
    float f = x - z;                        // frac in [-0.5, 0.5] (exact)
    float p = fmaf(f, fmaf(f, 0.33718944f, 0.65763628f), 1.0017247f);
    int sb = (__builtin_bit_cast(int, y) << 23) + 0x3F800000; // v_lshl_add_u32
    return p * __builtin_bit_cast(float, sb);
}

__global__ __launch_bounds__(256, 4) void bilateral_kernel(
    const float* __restrict__ img, const float* __restrict__ params,
    float* __restrict__ out)
{
    __shared__ float4 tile[PL];

    const int n  = blockIdx.z;
    const int x0 = blockIdx.x * TSX;
    const int y0 = blockIdx.y * TSY;

    const float p0 = params[n*3 + 0];
    const float p1 = params[n*3 + 1];
    const float p2 = params[n*3 + 2];
    const int win = ((int)p0) * 14 + 3;       // window = int(p0)*7*2 + 3
    const int r   = (win - 1) >> 1;
    const float sc = fmaf(p1, 99.0f, 1.0f);
    const float ss = fmaf(p2, 99.0f, 1.0f);
    const float LOG2E = 1.4426950408889634f;
    const float A  = -65025.0f * LOG2E / (2.0f * sc * sc);  // A < 0
    const float Bs = -LOG2E / (2.0f * ss * ss);

    // ---- stage tile + halo; w = q = A*(s.s) ----
    const float* imgN = img + (size_t)n * (3 * H * W);
    for (int idx = threadIdx.x; idx < PL; idx += 256) {
        int ly = idx / LW;
        int lx = idx - ly * LW;
        int gy = y0 + ly - RM; gy = gy < 0 ? 0 : (gy > H-1 ? H-1 : gy);
        int gx = x0 + lx - RM; gx = gx < 0 ? 0 : (gx > W-1 ? W-1 : gx);
        int g = gy * W + gx;
        float vr = imgN[g];
        float vg = imgN[H*W + g];
        float vb = imgN[2*H*W + g];
        tile[idx] = make_float4(vr, vg, vb,
                                A * fmaf(vr, vr, fmaf(vg, vg, vb * vb)));
    }
    __syncthreads();

    const int tx   = threadIdx.x & (TSX - 1);
    const int tq   = threadIdx.x >> 5;        // 0..7
    const int base = tq * PPT;

    // per-center constants — named scalars only (R4 lesson: no pointer-passed
    // arrays / helper functions -> no SROA failure -> no scratch)
    const float m2A = -2.0f * A;
    float4 c0 = tile[(RM + base + 0) * LW + (RM + tx)];
    float4 c1 = tile[(RM + base + 1) * LW + (RM + tx)];
    const float K0  = c0.w,        K1  = c1.w;
    const float r20 = m2A * c0.x,  r21 = m2A * c1.x;
    const float g20 = m2A * c0.y,  g21 = m2A * c1.y;
    const float b20 = m2A * c0.z,  b21 = m2A * c1.z;

    float a0r = 0.0f, a0g = 0.0f, a0b = 0.0f, a0d = 0.0f;
    float a1r = 0.0f, a1g = 0.0f, a1b = 0.0f, a1d = 0.0f;

    // spatial-x bias (block-uniform); constant-indexed after unroll
    float bx[2*RM + 1];
    #pragma unroll
    for (int i = 0; i <= 2*RM; ++i) {
        int d  = i - RM;
        int ad = d < 0 ? -d : d;
        bx[i] = (ad <= r) ? Bs * (float)(d*d) : BIGNEG;
    }

    #pragma unroll 1
    for (int j = 0; j < 2*RM + PPT; ++j) {    // 18 rows
        int dy0 = j - RM;                     // center 0
        int dy1 = j - RM - 1;                 // center 1
        int ad0 = dy0 < 0 ? -dy0 : dy0;
        int ad1 = dy1 < 0 ? -dy1 : dy1;
        const float ck0 = K0 + ((ad0 <= r) ? Bs * (float)(dy0*dy0) : BIGNEG);
        const float ck1 = K1 + ((ad1 <= r) ? Bs * (float)(dy1*dy1) : BIGNEG);

        const int rb = (base + j) * LW + tx;
        #pragma unroll
        for (int i = 0; i <= 2*RM; ++i) {
            float4 s = tile[rb + i];          // ds_read_b128
            float qb = s.w + bx[i];           // shared across both centers

            float t0 = fmaf(b20, s.z, ck0);
            t0 = fmaf(g20, s.y, t0);
            t0 = fmaf(r20, s.x, t0);
            float x0v = fmaxf(t0 + qb, -126.0f);
            float w0 = exp2_fast(x0v);
            a0r = fmaf(w0, s.x, a0r);
            a0g = fmaf(w0, s.y, a0g);
            a0b = fmaf(w0, s.z, a0b);
            a0d += w0;

            float t1 = fmaf(b21, s.z, ck1);
            t1 = fmaf(g21, s.y, t1);
            t1 = fmaf(r21, s.x, t1);
            float x1v = fmaxf(t1 + qb, -126.0f);
            float w1 = exp2_fast(x1v);
            a1r = fmaf(w1, s.x, a1r);
            a1g = fmaf(w1, s.y, a1g);
            a1b = fmaf(w1, s.z, a1b);
            a1d += w1;
        }
    }

    float* outN = out + (size_t)n * (3 * H * W);
    const float inv0 = __builtin_amdgcn_rcpf(a0d);
    const float inv1 = __builtin_amdgcn_rcpf(a1d);
    const int o0 = (y0 + base + 0) * W + (x0 + tx);
    const int o1 = (y0 + base + 1) * W + (x0 + tx);
    outN[o0]         = a0r * inv0;
    outN[H*W + o0]   = a0g * inv0;
    outN[2*H*W + o0] = a0b * inv0;
    outN[o1]         = a1r * inv1;
    outN[H*W + o1]   = a1g * inv1;
    outN[2*H*W + o1] = a1b * inv1;
}

extern "C" void kernel_launch(void* const* d_in, const int* in_sizes, int n_in,
                              void* d_out, int out_size, void* d_ws, size_t ws_size,
                              hipStream_t stream) {
    const float* img    = (const float*)d_in[0];
    const float* params = (const float*)d_in[1];
    float* out          = (float*)d_out;
    dim3 grid(W / TSX, H / TSY, 8);
    bilateral_kernel<<<grid, dim3(256), 0, stream>>>(img, params, out);
}